// Round 1
// baseline (238.878 us; speedup 1.0000x reference)
//
#include <hip/hip_runtime.h>

#define NV 512
#define BV 8
#define HV 64
#define KSEL 26163
#define NNv (NV*NV)          // 262144
#define BKv (BV*KSEL)        // 209304

typedef unsigned int u32;

// ---------------- init: zero histograms, set per-batch state ----------------
__global__ void k_init(u32* __restrict__ hist4, u32* __restrict__ prefix,
                       u32* __restrict__ remK) {
    const int t = blockIdx.x * 256 + threadIdx.x;
    if (t < 8192) hist4[t] = 0u;          // 4 passes x 8 batches x 256 bins
    if (t < 8) { prefix[t] = 0u; remK[t] = (u32)KSEL; }
}

// ---------------- embed: x -> emb -> ai, aj (4096 rows x 64) ----------------
__global__ void __launch_bounds__(256) k_embed(
    const float* __restrict__ x, const float* __restrict__ w_emb,
    const float* __restrict__ b_emb, const float* __restrict__ w_proj,
    const float* __restrict__ b_proj, const float* __restrict__ w1,
    float* __restrict__ ai, float* __restrict__ aj) {
    __shared__ float sh[4][64];
    __shared__ float se[4][64];
    const int c = threadIdx.x;        // 0..63
    const int lr = threadIdx.y;       // 0..3
    const int row = blockIdx.x * 4 + lr;
    const float xv = x[row];
    sh[lr][c] = fmaxf(fmaf(xv, w_emb[c], b_emb[c]), 0.f);
    __syncthreads();
    float e = 0.f;
#pragma unroll
    for (int h = 0; h < 64; ++h) e = fmaf(sh[lr][h], w_proj[h * 64 + c], e);
    se[lr][c] = e + b_proj[c];
    __syncthreads();
    float a0 = 0.f, a1 = 0.f;
#pragma unroll
    for (int h = 0; h < 64; ++h) {
        const float ev = se[lr][h];
        a0 = fmaf(ev, w1[h * 64 + c], a0);
        a1 = fmaf(ev, w1[(64 + h) * 64 + c], a1);
    }
    ai[row * 64 + c] = a0;
    aj[row * 64 + c] = a1;
}

// ---------------- pair scorer: probs[b][i][j] = sigmoid(mlp(ai_i, aj_j)) ----
__global__ void __launch_bounds__(256, 2) k_pairs(
    const float* __restrict__ ai, const float* __restrict__ aj,
    const float* __restrict__ b1, const float* __restrict__ w2,
    const float* __restrict__ b2, const float* __restrict__ w3,
    const float* __restrict__ b3, float* __restrict__ probs) {
    __shared__ float s_ai[16 * 65];
    __shared__ float s_aj[32 * 65];
    __shared__ float s_b1[64];
    __shared__ float s_w2[64 * 32];
    __shared__ float s_b2[32];
    __shared__ float s_w3[32];
    __shared__ float s_b3v;
    const int tid = threadIdx.x;
    const int b  = blockIdx.z;
    const int i0 = blockIdx.y << 4;   // 16 i per block
    const int j0 = blockIdx.x << 5;   // 32 j per block

    {
        const int r  = tid >> 4;          // 0..15
        const int h4 = (tid & 15) << 2;   // 0,4,...,60
        float4 v = *(const float4*)&ai[(((b << 9) + i0 + r) << 6) + h4];
        *(float4*)&s_ai[r * 65 + h4] = v;
        float4 u0 = *(const float4*)&aj[(((b << 9) + j0 + r) << 6) + h4];
        *(float4*)&s_aj[r * 65 + h4] = u0;
        float4 u1 = *(const float4*)&aj[(((b << 9) + j0 + 16 + r) << 6) + h4];
        *(float4*)&s_aj[(r + 16) * 65 + h4] = u1;
        *(float4*)&s_w2[tid * 4]        = *(const float4*)&w2[tid * 4];
        *(float4*)&s_w2[1024 + tid * 4] = *(const float4*)&w2[1024 + tid * 4];
        if (tid < 64) s_b1[tid] = b1[tid];
        if (tid < 32) { s_b2[tid] = b2[tid]; s_w3[tid] = w3[tid]; }
        if (tid == 0) s_b3v = b3[0];
    }
    __syncthreads();

    const int tj = tid & 15;
    const int ti = tid >> 4;
    const float* __restrict__ Ai = &s_ai[ti * 65];
    const float* __restrict__ A0 = &s_aj[tj * 65];
    const float* __restrict__ A1 = &s_aj[(tj + 16) * 65];

    float acc0[32], acc1[32];
#pragma unroll
    for (int k = 0; k < 32; ++k) { acc0[k] = 0.f; acc1[k] = 0.f; }

#pragma unroll 4
    for (int h = 0; h < 64; ++h) {
        const float aiv = Ai[h];
        const float bv  = s_b1[h];
        const float t0 = fmaxf((aiv + A0[h]) + bv, 0.f);
        const float t1 = fmaxf((aiv + A1[h]) + bv, 0.f);
        const float* __restrict__ wr = &s_w2[h << 5];
#pragma unroll
        for (int k = 0; k < 32; ++k) {
            const float w = wr[k];
            acc0[k] = fmaf(t0, w, acc0[k]);
            acc1[k] = fmaf(t1, w, acc1[k]);
        }
    }

    float d0 = 0.f, d1 = 0.f;
#pragma unroll
    for (int k = 0; k < 32; ++k) {
        const float bk = s_b2[k], wk = s_w3[k];
        d0 = fmaf(fmaxf(acc0[k] + bk, 0.f), wk, d0);
        d1 = fmaf(fmaxf(acc1[k] + bk, 0.f), wk, d1);
    }
    const float p0 = 1.f / (1.f + expf(-(d0 + s_b3v)));
    const float p1 = 1.f / (1.f + expf(-(d1 + s_b3v)));
    const int base = (((b << 9) + i0 + ti) << 9) + j0 + tj;
    probs[base]      = p0;
    probs[base + 16] = p1;
}

// ---------------- symmetrize in place, zero diagonal ------------------------
__global__ void k_sym(float* __restrict__ P) {
    const int b = blockIdx.y;
    int rem = blockIdx.x, ta = 0;
    while (rem >= 16 - ta) { rem -= 16 - ta; ++ta; }
    const int tb = ta + rem;                 // ta <= tb, 32x32 tiles
    const int r  = threadIdx.x >> 3;         // 0..31
    const int c4 = (threadIdx.x & 7) << 2;   // 0,4,...,28
    const int i = (ta << 5) + r;
    const int j = (tb << 5) + c4;
    float* Pb = P + b * NNv;
    float4 a = *(const float4*)&Pb[(i << 9) + j];
    float t0 = Pb[((j + 0) << 9) + i];
    float t1 = Pb[((j + 1) << 9) + i];
    float t2 = Pb[((j + 2) << 9) + i];
    float t3 = Pb[((j + 3) << 9) + i];
    __syncthreads();   // all reads complete before any in-place writes
    float4 o;
    o.x = (i == j + 0) ? 0.f : 0.5f * (a.x + t0);
    o.y = (i == j + 1) ? 0.f : 0.5f * (a.y + t1);
    o.z = (i == j + 2) ? 0.f : 0.5f * (a.z + t2);
    o.w = (i == j + 3) ? 0.f : 0.5f * (a.w + t3);
    *(float4*)&Pb[(i << 9) + j] = o;
    Pb[((j + 0) << 9) + i] = o.x;
    Pb[((j + 1) << 9) + i] = o.y;
    Pb[((j + 2) << 9) + i] = o.z;
    Pb[((j + 3) << 9) + i] = o.w;
}

// ---------------- radix-select (4 passes of 8 bits) -------------------------
template <int P>
__global__ void k_hist(const float* __restrict__ probs,
                       const u32* __restrict__ prefix, u32* __restrict__ hist) {
    __shared__ u32 lh[256];
    const int t = threadIdx.x;
    lh[t] = 0u;
    __syncthreads();
    const int b = blockIdx.y;
    u32 pref = 0u;
    if constexpr (P > 0) pref = prefix[b];
    const float* Pb = probs + b * NNv;
    const int base = blockIdx.x * 4096 + t;
#pragma unroll
    for (int e = 0; e < 16; ++e) {
        const u32 key = __float_as_uint(Pb[base + e * 256]);
        bool ok = true;
        if constexpr (P > 0) ok = ((key >> (32 - 8 * P)) == pref);
        if (ok) atomicAdd(&lh[(key >> (24 - 8 * P)) & 255u], 1u);
    }
    __syncthreads();
    if (lh[t]) atomicAdd(&hist[b * 256 + t], lh[t]);
}

__global__ void k_sel(const u32* __restrict__ hist, u32* __restrict__ prefix,
                      u32* __restrict__ remK) {
    const int b = threadIdx.x;
    if (b >= 8) return;
    const u32 rem = remK[b];
    u32 acc = 0;
    int c = 255;
    for (; c > 0; --c) {
        const u32 hv = hist[b * 256 + c];
        if (acc + hv >= rem) break;
        acc += hv;
    }
    remK[b] = rem - acc;                       // rank within chosen bin
    prefix[b] = (prefix[b] << 8) | (u32)c;
}

// ---------------- stable compaction of selected edges -----------------------
__global__ void k_count(const float* __restrict__ P, const u32* __restrict__ Tk,
                        u32* __restrict__ bgt, u32* __restrict__ beq) {
    __shared__ u32 sg[256], se[256];
    const int b = blockIdx.y, blk = blockIdx.x, t = threadIdx.x;
    const u32 T = Tk[b];
    const float4 v = *(const float4*)&P[b * NNv + blk * 1024 + t * 4];
    const u32 k0 = __float_as_uint(v.x), k1 = __float_as_uint(v.y);
    const u32 k2 = __float_as_uint(v.z), k3 = __float_as_uint(v.w);
    sg[t] = (u32)(k0 > T) + (k1 > T) + (k2 > T) + (k3 > T);
    se[t] = (u32)(k0 == T) + (k1 == T) + (k2 == T) + (k3 == T);
    __syncthreads();
    for (int s = 128; s > 0; s >>= 1) {
        if (t < s) { sg[t] += sg[t + s]; se[t] += se[t + s]; }
        __syncthreads();
    }
    if (t == 0) { bgt[b * 256 + blk] = sg[0]; beq[b * 256 + blk] = se[0]; }
}

__global__ void k_scan(const u32* __restrict__ bgt, const u32* __restrict__ beq,
                       u32* __restrict__ goff, u32* __restrict__ eoff) {
    const int b = threadIdx.x;
    if (b >= 8) return;
    u32 sg = 0, se = 0;
    for (int k = 0; k < 256; ++k) {
        goff[b * 256 + k] = sg; sg += bgt[b * 256 + k];
        eoff[b * 256 + k] = se; se += beq[b * 256 + k];
    }
}

__global__ void k_write(const float* __restrict__ P, const u32* __restrict__ Tk,
                        const u32* __restrict__ Rk, const u32* __restrict__ goff,
                        const u32* __restrict__ eoff, float* __restrict__ out) {
    __shared__ u32 sg[256], se[256];
    const int b = blockIdx.y, blk = blockIdx.x, t = threadIdx.x;
    const u32 T = Tk[b];
    const u32 R = Rk[b];
    const int pbase = b * NNv;
    const int fi0 = blk * 1024 + t * 4;
    const float4 v = *(const float4*)&P[pbase + fi0];
    float vv[4] = {v.x, v.y, v.z, v.w};
    u32 kk[4];
#pragma unroll
    for (int q = 0; q < 4; ++q) kk[q] = __float_as_uint(vv[q]);
    u32 gt = 0, eq = 0;
#pragma unroll
    for (int q = 0; q < 4; ++q) { gt += (kk[q] > T); eq += (kk[q] == T); }
    sg[t] = gt; se[t] = eq;
    __syncthreads();
    for (int off = 1; off < 256; off <<= 1) {
        const u32 ag = (t >= off) ? sg[t - off] : 0u;
        const u32 ae = (t >= off) ? se[t - off] : 0u;
        __syncthreads();
        sg[t] += ag; se[t] += ae;
        __syncthreads();
    }
    u32 gt_before = goff[b * 256 + blk] + sg[t] - gt;
    u32 eq_before = eoff[b * 256 + blk] + se[t] - eq;
#pragma unroll
    for (int q = 0; q < 4; ++q) {
        const u32 key = kk[q];
        const float val = vv[q];
        const bool selg = key > T;
        const bool sele = (key == T) && (eq_before < R);
        if (selg || sele) {
            const u32 ties = (eq_before < R) ? eq_before : R;
            const u32 pos = selg ? (gt_before + ties) : (gt_before + eq_before);
            const int g = b * KSEL + (int)pos;
            const int fi = fi0 + q;
            const int row = fi >> 9, col = fi & 511;
            out[g]            = (float)(row + (b << 9));
            out[BKv + g]      = (float)(col + (b << 9));
            out[2 * BKv + g]  = val;
            out[3 * BKv + pbase + fi] = val;
        }
        gt_before += (u32)selg;
        eq_before += (u32)(key == T);
    }
}

// ---------------------------------------------------------------------------
extern "C" void kernel_launch(void* const* d_in, const int* in_sizes, int n_in,
                              void* d_out, int out_size, void* d_ws, size_t ws_size,
                              hipStream_t stream) {
    const float* x      = (const float*)d_in[0];
    const float* w_emb  = (const float*)d_in[1];
    const float* b_emb  = (const float*)d_in[2];
    const float* w_proj = (const float*)d_in[3];
    const float* b_proj = (const float*)d_in[4];
    const float* w1     = (const float*)d_in[5];
    const float* b1     = (const float*)d_in[6];
    const float* w2     = (const float*)d_in[7];
    const float* b2     = (const float*)d_in[8];
    const float* w3     = (const float*)d_in[9];
    const float* b3     = (const float*)d_in[10];
    (void)in_sizes; (void)n_in; (void)ws_size;

    char* ws = (char*)d_ws;
    float* ai    = (float*)(ws);                    // 1 MiB
    float* aj    = (float*)(ws + 1048576);          // 1 MiB
    float* probs = (float*)(ws + 2097152);          // 8 MiB
    u32* hist4  = (u32*)(ws + 10485760);            // 32 KiB (4 passes)
    u32* prefix = (u32*)(ws + 10518528);            // 32 B
    u32* remK   = (u32*)(ws + 10518560);            // 32 B
    u32* bgt    = (u32*)(ws + 10518592);            // 8 KiB
    u32* beq    = (u32*)(ws + 10526784);            // 8 KiB
    u32* goff   = (u32*)(ws + 10534976);            // 8 KiB
    u32* eoff   = (u32*)(ws + 10543168);            // 8 KiB

    float* out = (float*)d_out;

    hipMemsetAsync(d_out, 0, (size_t)out_size * sizeof(float), stream);
    k_init<<<32, 256, 0, stream>>>(hist4, prefix, remK);
    k_embed<<<1024, dim3(64, 4, 1), 0, stream>>>(x, w_emb, b_emb, w_proj, b_proj, w1, ai, aj);
    k_pairs<<<dim3(16, 32, 8), 256, 0, stream>>>(ai, aj, b1, w2, b2, w3, b3, probs);
    k_sym<<<dim3(136, 8), 256, 0, stream>>>(probs);
    k_hist<0><<<dim3(64, 8), 256, 0, stream>>>(probs, prefix, hist4);
    k_sel<<<1, 64, 0, stream>>>(hist4, prefix, remK);
    k_hist<1><<<dim3(64, 8), 256, 0, stream>>>(probs, prefix, hist4 + 2048);
    k_sel<<<1, 64, 0, stream>>>(hist4 + 2048, prefix, remK);
    k_hist<2><<<dim3(64, 8), 256, 0, stream>>>(probs, prefix, hist4 + 4096);
    k_sel<<<1, 64, 0, stream>>>(hist4 + 4096, prefix, remK);
    k_hist<3><<<dim3(64, 8), 256, 0, stream>>>(probs, prefix, hist4 + 6144);
    k_sel<<<1, 64, 0, stream>>>(hist4 + 6144, prefix, remK);
    k_count<<<dim3(256, 8), 256, 0, stream>>>(probs, prefix, bgt, beq);
    k_scan<<<1, 64, 0, stream>>>(bgt, beq, goff, eoff);
    k_write<<<dim3(256, 8), 256, 0, stream>>>(probs, prefix, remK, goff, eoff, out);
}

// Round 2
// 170.889 us; speedup vs baseline: 1.3979x; 1.3979x over previous
//
#include <hip/hip_runtime.h>

#define NV 512
#define BV 8
#define HV 64
#define KSEL 26163
#define NNv (NV*NV)          // 262144
#define BKv (BV*KSEL)        // 209304

typedef unsigned int u32;
typedef __attribute__((ext_vector_type(2))) float f32x2;

// ---------------- init: zero histograms, set per-batch state ----------------
__global__ void k_init(u32* __restrict__ hist4, u32* __restrict__ prefix,
                       u32* __restrict__ remK) {
    const int t = blockIdx.x * 256 + threadIdx.x;
    if (t < 8192) hist4[t] = 0u;          // 4 passes x 8 batches x 256 bins
    if (t < 8) { prefix[t] = 0u; remK[t] = (u32)KSEL; }
}

// ---------------- embed: x -> emb -> ai, aj (4096 rows x 64) ----------------
__global__ void __launch_bounds__(256) k_embed(
    const float* __restrict__ x, const float* __restrict__ w_emb,
    const float* __restrict__ b_emb, const float* __restrict__ w_proj,
    const float* __restrict__ b_proj, const float* __restrict__ w1,
    float* __restrict__ ai, float* __restrict__ aj) {
    __shared__ float sh[4][64];
    __shared__ float se[4][64];
    const int c = threadIdx.x;        // 0..63
    const int lr = threadIdx.y;       // 0..3
    const int row = blockIdx.x * 4 + lr;
    const float xv = x[row];
    sh[lr][c] = fmaxf(fmaf(xv, w_emb[c], b_emb[c]), 0.f);
    __syncthreads();
    float e = 0.f;
#pragma unroll
    for (int h = 0; h < 64; ++h) e = fmaf(sh[lr][h], w_proj[h * 64 + c], e);
    se[lr][c] = e + b_proj[c];
    __syncthreads();
    float a0 = 0.f, a1 = 0.f;
#pragma unroll
    for (int h = 0; h < 64; ++h) {
        const float ev = se[lr][h];
        a0 = fmaf(ev, w1[h * 64 + c], a0);
        a1 = fmaf(ev, w1[(64 + h) * 64 + c], a1);
    }
    ai[row * 64 + c] = a0;
    aj[row * 64 + c] = a1;
}

// ---------------- pair scorer: probs[b][i][j] = sigmoid(mlp(ai_i, aj_j)) ----
// 16 i x 64 j tile per block; each thread: 1 i, 4 j (j, j+16, j+32, j+48).
// Inner contraction uses packed v_pk_fma_f32 (2 FMAs/instr); per-k fma chain
// over h is bit-identical to the scalar version (selection-safe).
#define F4(v, c) (((const float*)&(v))[c])
__global__ void __launch_bounds__(256, 2) k_pairs(
    const float* __restrict__ ai, const float* __restrict__ aj,
    const float* __restrict__ b1, const float* __restrict__ w2,
    const float* __restrict__ b2, const float* __restrict__ w3,
    const float* __restrict__ b3, float* __restrict__ probs) {
    __shared__ float s_ai[16 * 68];
    __shared__ float s_aj[64 * 68];
    __shared__ float s_b1[64];
    __shared__ float s_w2[64 * 32];
    __shared__ float s_b2[32];
    __shared__ float s_w3[32];
    __shared__ float s_b3v;
    const int tid = threadIdx.x;
    const int b  = blockIdx.z;
    const int i0 = blockIdx.y << 4;   // 16 i per block
    const int j0 = blockIdx.x << 6;   // 64 j per block

    {
        const int r  = tid >> 4;          // 0..15
        const int q4 = (tid & 15) << 2;   // 0,4,...,60
        *(float4*)&s_ai[r * 68 + q4] =
            *(const float4*)&ai[(((b << 9) + i0 + r) << 6) + q4];
#pragma unroll
        for (int s = 0; s < 4; ++s) {
            *(float4*)&s_aj[(r + 16 * s) * 68 + q4] =
                *(const float4*)&aj[(((b << 9) + j0 + 16 * s + r) << 6) + q4];
        }
        *(float4*)&s_w2[tid * 4]        = *(const float4*)&w2[tid * 4];
        *(float4*)&s_w2[1024 + tid * 4] = *(const float4*)&w2[1024 + tid * 4];
        if (tid < 64) s_b1[tid] = b1[tid];
        if (tid < 32) { s_b2[tid] = b2[tid]; s_w3[tid] = w3[tid]; }
        if (tid == 0) s_b3v = b3[0];
    }
    __syncthreads();

    const int tj = tid & 15;
    const int ti = tid >> 4;

    f32x2 acc0[16], acc1[16], acc2[16], acc3[16];
#pragma unroll
    for (int k = 0; k < 16; ++k) {
        acc0[k] = (f32x2){0.f, 0.f}; acc1[k] = (f32x2){0.f, 0.f};
        acc2[k] = (f32x2){0.f, 0.f}; acc3[k] = (f32x2){0.f, 0.f};
    }

#pragma unroll 1
    for (int h4 = 0; h4 < 64; h4 += 4) {
        const float4 aiv = *(const float4*)&s_ai[ti * 68 + h4];
        const float4 aj0 = *(const float4*)&s_aj[(tj     ) * 68 + h4];
        const float4 aj1 = *(const float4*)&s_aj[(tj + 16) * 68 + h4];
        const float4 aj2 = *(const float4*)&s_aj[(tj + 32) * 68 + h4];
        const float4 aj3 = *(const float4*)&s_aj[(tj + 48) * 68 + h4];
        const float4 b1v = *(const float4*)&s_b1[h4];
#pragma unroll
        for (int hh = 0; hh < 4; ++hh) {
            const float ah = F4(aiv, hh);
            const float bh = F4(b1v, hh);
            const float t0 = fmaxf((ah + F4(aj0, hh)) + bh, 0.f);
            const float t1 = fmaxf((ah + F4(aj1, hh)) + bh, 0.f);
            const float t2 = fmaxf((ah + F4(aj2, hh)) + bh, 0.f);
            const float t3 = fmaxf((ah + F4(aj3, hh)) + bh, 0.f);
            const f32x2 tt0 = {t0, t0};
            const f32x2 tt1 = {t1, t1};
            const f32x2 tt2 = {t2, t2};
            const f32x2 tt3 = {t3, t3};
            const float4* w4p = (const float4*)&s_w2[(h4 + hh) << 5];
            f32x2 w2r[16];
#pragma unroll
            for (int q = 0; q < 8; ++q) {
                const float4 w = w4p[q];
                w2r[2 * q]     = (f32x2){w.x, w.y};
                w2r[2 * q + 1] = (f32x2){w.z, w.w};
            }
#pragma unroll
            for (int k = 0; k < 16; ++k) {
                asm("v_pk_fma_f32 %0, %1, %2, %0" : "+v"(acc0[k]) : "v"(w2r[k]), "v"(tt0));
                asm("v_pk_fma_f32 %0, %1, %2, %0" : "+v"(acc1[k]) : "v"(w2r[k]), "v"(tt1));
                asm("v_pk_fma_f32 %0, %1, %2, %0" : "+v"(acc2[k]) : "v"(w2r[k]), "v"(tt2));
                asm("v_pk_fma_f32 %0, %1, %2, %0" : "+v"(acc3[k]) : "v"(w2r[k]), "v"(tt3));
            }
        }
    }

    // Epilogue: scalar, strictly sequential over k (identical order to the
    // passing reference kernel -> bit-identical probs -> identical top-K).
    float d0 = 0.f, d1 = 0.f, d2 = 0.f, d3 = 0.f;
#pragma unroll
    for (int k = 0; k < 32; ++k) {
        const float bk = s_b2[k], wk = s_w3[k];
        d0 = fmaf(fmaxf(acc0[k >> 1][k & 1] + bk, 0.f), wk, d0);
        d1 = fmaf(fmaxf(acc1[k >> 1][k & 1] + bk, 0.f), wk, d1);
        d2 = fmaf(fmaxf(acc2[k >> 1][k & 1] + bk, 0.f), wk, d2);
        d3 = fmaf(fmaxf(acc3[k >> 1][k & 1] + bk, 0.f), wk, d3);
    }
    const float bb = s_b3v;
    const float p0 = 1.f / (1.f + expf(-(d0 + bb)));
    const float p1 = 1.f / (1.f + expf(-(d1 + bb)));
    const float p2 = 1.f / (1.f + expf(-(d2 + bb)));
    const float p3 = 1.f / (1.f + expf(-(d3 + bb)));
    const int base = (((b << 9) + i0 + ti) << 9) + j0 + tj;
    probs[base]      = p0;
    probs[base + 16] = p1;
    probs[base + 32] = p2;
    probs[base + 48] = p3;
}

// ---------------- symmetrize in place, zero diagonal ------------------------
__global__ void k_sym(float* __restrict__ P) {
    const int b = blockIdx.y;
    int rem = blockIdx.x, ta = 0;
    while (rem >= 16 - ta) { rem -= 16 - ta; ++ta; }
    const int tb = ta + rem;                 // ta <= tb, 32x32 tiles
    const int r  = threadIdx.x >> 3;         // 0..31
    const int c4 = (threadIdx.x & 7) << 2;   // 0,4,...,28
    const int i = (ta << 5) + r;
    const int j = (tb << 5) + c4;
    float* Pb = P + b * NNv;
    float4 a = *(const float4*)&Pb[(i << 9) + j];
    float t0 = Pb[((j + 0) << 9) + i];
    float t1 = Pb[((j + 1) << 9) + i];
    float t2 = Pb[((j + 2) << 9) + i];
    float t3 = Pb[((j + 3) << 9) + i];
    __syncthreads();   // all reads complete before any in-place writes
    float4 o;
    o.x = (i == j + 0) ? 0.f : 0.5f * (a.x + t0);
    o.y = (i == j + 1) ? 0.f : 0.5f * (a.y + t1);
    o.z = (i == j + 2) ? 0.f : 0.5f * (a.z + t2);
    o.w = (i == j + 3) ? 0.f : 0.5f * (a.w + t3);
    *(float4*)&Pb[(i << 9) + j] = o;
    Pb[((j + 0) << 9) + i] = o.x;
    Pb[((j + 1) << 9) + i] = o.y;
    Pb[((j + 2) << 9) + i] = o.z;
    Pb[((j + 3) << 9) + i] = o.w;
}

// ---------------- radix-select (4 passes of 8 bits) -------------------------
template <int P>
__global__ void k_hist(const float* __restrict__ probs,
                       const u32* __restrict__ prefix, u32* __restrict__ hist) {
    __shared__ u32 lh[1024];                 // 4 replicas x 256 bins
    const int t = threadIdx.x;
    lh[t] = 0u; lh[256 + t] = 0u; lh[512 + t] = 0u; lh[768 + t] = 0u;
    __syncthreads();
    const int b = blockIdx.y;
    u32 pref = 0u;
    if constexpr (P > 0) pref = prefix[b];
    const float* Pb = probs + b * NNv;
    const int base = blockIdx.x * 4096 + t;
    const int rep = (t & 3) << 8;
#pragma unroll
    for (int e = 0; e < 16; ++e) {
        const u32 key = __float_as_uint(Pb[base + e * 256]);
        bool ok = true;
        if constexpr (P > 0) ok = ((key >> (32 - 8 * P)) == pref);
        if (ok) atomicAdd(&lh[rep + ((key >> (24 - 8 * P)) & 255u)], 1u);
    }
    __syncthreads();
    const u32 sum = lh[t] + lh[256 + t] + lh[512 + t] + lh[768 + t];
    if (sum) atomicAdd(&hist[b * 256 + t], sum);
}

// parallel suffix-scan select: one block per batch
__global__ void k_sel(const u32* __restrict__ hist, u32* __restrict__ prefix,
                      u32* __restrict__ remK) {
    __shared__ u32 s[256];
    __shared__ int cstar;
    const int b = blockIdx.x, t = threadIdx.x;
    const u32 h = hist[b * 256 + t];
    s[t] = h;
    if (t == 0) cstar = 0;
    __syncthreads();
    // inclusive suffix sums: s[t] = sum_{c>=t} h[c]
    for (int off = 1; off < 256; off <<= 1) {
        const u32 v = (t + off < 256) ? s[t + off] : 0u;
        __syncthreads();
        s[t] += v;
        __syncthreads();
    }
    const u32 rem = remK[b];
    if (s[t] >= rem) atomicMax(&cstar, t);
    __syncthreads();
    if (t == cstar) {
        const u32 above = (t < 255) ? s[t + 1] : 0u;
        remK[b] = rem - above;                  // rank within chosen bin
        prefix[b] = (prefix[b] << 8) | (u32)t;
    }
}

// ---------------- stable compaction of selected edges -----------------------
__global__ void k_count(const float* __restrict__ P, const u32* __restrict__ Tk,
                        u32* __restrict__ bgt, u32* __restrict__ beq) {
    __shared__ u32 sg[256], se[256];
    const int b = blockIdx.y, blk = blockIdx.x, t = threadIdx.x;
    const u32 T = Tk[b];
    const float4 v = *(const float4*)&P[b * NNv + blk * 1024 + t * 4];
    const u32 k0 = __float_as_uint(v.x), k1 = __float_as_uint(v.y);
    const u32 k2 = __float_as_uint(v.z), k3 = __float_as_uint(v.w);
    sg[t] = (u32)(k0 > T) + (k1 > T) + (k2 > T) + (k3 > T);
    se[t] = (u32)(k0 == T) + (k1 == T) + (k2 == T) + (k3 == T);
    __syncthreads();
    for (int s = 128; s > 0; s >>= 1) {
        if (t < s) { sg[t] += sg[t + s]; se[t] += se[t + s]; }
        __syncthreads();
    }
    if (t == 0) { bgt[b * 256 + blk] = sg[0]; beq[b * 256 + blk] = se[0]; }
}

// parallel per-batch exclusive scan of the 256 block totals
__global__ void k_scan(const u32* __restrict__ bgt, const u32* __restrict__ beq,
                       u32* __restrict__ goff, u32* __restrict__ eoff) {
    __shared__ u32 sg[256], se[256];
    const int b = blockIdx.x, t = threadIdx.x;
    const u32 g = bgt[b * 256 + t], e = beq[b * 256 + t];
    sg[t] = g; se[t] = e;
    __syncthreads();
    for (int off = 1; off < 256; off <<= 1) {
        const u32 ag = (t >= off) ? sg[t - off] : 0u;
        const u32 ae = (t >= off) ? se[t - off] : 0u;
        __syncthreads();
        sg[t] += ag; se[t] += ae;
        __syncthreads();
    }
    goff[b * 256 + t] = sg[t] - g;   // exclusive
    eoff[b * 256 + t] = se[t] - e;
}

__global__ void k_write(const float* __restrict__ P, const u32* __restrict__ Tk,
                        const u32* __restrict__ Rk, const u32* __restrict__ goff,
                        const u32* __restrict__ eoff, float* __restrict__ out) {
    __shared__ u32 sg[256], se[256];
    const int b = blockIdx.y, blk = blockIdx.x, t = threadIdx.x;
    const u32 T = Tk[b];
    const u32 R = Rk[b];
    const int pbase = b * NNv;
    const int fi0 = blk * 1024 + t * 4;
    const float4 v = *(const float4*)&P[pbase + fi0];
    float vv[4] = {v.x, v.y, v.z, v.w};
    u32 kk[4];
#pragma unroll
    for (int q = 0; q < 4; ++q) kk[q] = __float_as_uint(vv[q]);
    u32 gt = 0, eq = 0;
#pragma unroll
    for (int q = 0; q < 4; ++q) { gt += (kk[q] > T); eq += (kk[q] == T); }
    sg[t] = gt; se[t] = eq;
    __syncthreads();
    for (int off = 1; off < 256; off <<= 1) {
        const u32 ag = (t >= off) ? sg[t - off] : 0u;
        const u32 ae = (t >= off) ? se[t - off] : 0u;
        __syncthreads();
        sg[t] += ag; se[t] += ae;
        __syncthreads();
    }
    u32 gt_before = goff[b * 256 + blk] + sg[t] - gt;
    u32 eq_before = eoff[b * 256 + blk] + se[t] - eq;
#pragma unroll
    for (int q = 0; q < 4; ++q) {
        const u32 key = kk[q];
        const float val = vv[q];
        const bool selg = key > T;
        const bool sele = (key == T) && (eq_before < R);
        if (selg || sele) {
            const u32 ties = (eq_before < R) ? eq_before : R;
            const u32 pos = selg ? (gt_before + ties) : (gt_before + eq_before);
            const int g = b * KSEL + (int)pos;
            const int fi = fi0 + q;
            const int row = fi >> 9, col = fi & 511;
            out[g]            = (float)(row + (b << 9));
            out[BKv + g]      = (float)(col + (b << 9));
            out[2 * BKv + g]  = val;
            out[3 * BKv + pbase + fi] = val;
        }
        gt_before += (u32)selg;
        eq_before += (u32)(key == T);
    }
}

// ---------------------------------------------------------------------------
extern "C" void kernel_launch(void* const* d_in, const int* in_sizes, int n_in,
                              void* d_out, int out_size, void* d_ws, size_t ws_size,
                              hipStream_t stream) {
    const float* x      = (const float*)d_in[0];
    const float* w_emb  = (const float*)d_in[1];
    const float* b_emb  = (const float*)d_in[2];
    const float* w_proj = (const float*)d_in[3];
    const float* b_proj = (const float*)d_in[4];
    const float* w1     = (const float*)d_in[5];
    const float* b1     = (const float*)d_in[6];
    const float* w2     = (const float*)d_in[7];
    const float* b2     = (const float*)d_in[8];
    const float* w3     = (const float*)d_in[9];
    const float* b3     = (const float*)d_in[10];
    (void)in_sizes; (void)n_in; (void)ws_size;

    char* ws = (char*)d_ws;
    float* ai    = (float*)(ws);                    // 1 MiB
    float* aj    = (float*)(ws + 1048576);          // 1 MiB
    float* probs = (float*)(ws + 2097152);          // 8 MiB
    u32* hist4  = (u32*)(ws + 10485760);            // 32 KiB (4 passes)
    u32* prefix = (u32*)(ws + 10518528);            // 32 B
    u32* remK   = (u32*)(ws + 10518560);            // 32 B
    u32* bgt    = (u32*)(ws + 10518592);            // 8 KiB
    u32* beq    = (u32*)(ws + 10526784);            // 8 KiB
    u32* goff   = (u32*)(ws + 10534976);            // 8 KiB
    u32* eoff   = (u32*)(ws + 10543168);            // 8 KiB

    float* out = (float*)d_out;

    hipMemsetAsync(d_out, 0, (size_t)out_size * sizeof(float), stream);
    k_init<<<32, 256, 0, stream>>>(hist4, prefix, remK);
    k_embed<<<1024, dim3(64, 4, 1), 0, stream>>>(x, w_emb, b_emb, w_proj, b_proj, w1, ai, aj);
    k_pairs<<<dim3(8, 32, 8), 256, 0, stream>>>(ai, aj, b1, w2, b2, w3, b3, probs);
    k_sym<<<dim3(136, 8), 256, 0, stream>>>(probs);
    k_hist<0><<<dim3(64, 8), 256, 0, stream>>>(probs, prefix, hist4);
    k_sel<<<8, 256, 0, stream>>>(hist4, prefix, remK);
    k_hist<1><<<dim3(64, 8), 256, 0, stream>>>(probs, prefix, hist4 + 2048);
    k_sel<<<8, 256, 0, stream>>>(hist4 + 2048, prefix, remK);
    k_hist<2><<<dim3(64, 8), 256, 0, stream>>>(probs, prefix, hist4 + 4096);
    k_sel<<<8, 256, 0, stream>>>(hist4 + 4096, prefix, remK);
    k_hist<3><<<dim3(64, 8), 256, 0, stream>>>(probs, prefix, hist4 + 6144);
    k_sel<<<8, 256, 0, stream>>>(hist4 + 6144, prefix, remK);
    k_count<<<dim3(256, 8), 256, 0, stream>>>(probs, prefix, bgt, beq);
    k_scan<<<8, 256, 0, stream>>>(bgt, beq, goff, eoff);
    k_write<<<dim3(256, 8), 256, 0, stream>>>(probs, prefix, remK, goff, eoff, out);
}